// Round 3
// baseline (194.825 us; speedup 1.0000x reference)
//
#include <hip/hip_runtime.h>

// AttentionConv on MI355X.
// Phase 1: per-patch QKV GEMM  (M=8*64*64 patches, K=192, N=576), fp32 VALU.
//          Output stored in PIXEL layout: Q|K|V planes of [8][3][512][512] in d_ws.
// Phase 2: out = q * sum_{di,dj} fr(di,pi)*fc(dj,pj) * k_shift * v_shift
//          (±8-pixel shifted stencil; out-of-range neighbors use b_qkv constants).

#define HW 512
#define PLANE 6291456   // 8*3*512*512 floats per Q/K/V plane

__global__ void __launch_bounds__(256) qkv_gemm_kernel(
    const float* __restrict__ x,
    const float* __restrict__ W,     // [576][192]
    const float* __restrict__ bqkv,  // [576]
    float* __restrict__ ws)
{
    // BM=64 patches (one tile-row: fixed b,i, j=0..63), BN=64 e, BK=64 (=1 channel)
    __shared__ float As[64][68];   // As[k_local][j]
    __shared__ float Bs[64][68];   // Bs[k_local][e_local]

    const int tid = threadIdx.x;
    const int mb  = blockIdx.x;          // b*64 + i
    const int nb  = blockIdx.y;          // 0..8, e-chunk of 64
    const int b   = mb >> 6;
    const int i   = mb & 63;
    const int te  = tid & 15;            // e-quad
    const int tj  = tid >> 4;            // j-quad

    float acc[4][4];                     // [jj][ee]
    #pragma unroll
    for (int a_ = 0; a_ < 4; ++a_)
        #pragma unroll
        for (int b_ = 0; b_ < 4; ++b_) acc[a_][b_] = 0.f;

    for (int kt = 0; kt < 3; ++kt) {     // k-pass == channel kt (d = kt*64 + pi*8+pj)
        // ---- stage A: x[b][kt][i*8 .. i*8+7][0..511]  (4096 contiguous floats) ----
        const float4* xs = (const float4*)(x + (((size_t)(b*3 + kt))*HW + (size_t)i*8) * HW);
        #pragma unroll
        for (int it = 0; it < 4; ++it) {
            int f = tid + it*256;              // float4 index 0..1023
            float4 a = xs[f];
            int pi  = f >> 7;                  // 128 float4 per image row
            int col = (f & 127) << 2;          // 0..508, %4==0 -> stays in one pj-octet
            int j   = col >> 3;
            int kl  = pi*8 + (col & 7);
            As[kl+0][j] = a.x;
            As[kl+1][j] = a.y;
            As[kl+2][j] = a.z;
            As[kl+3][j] = a.w;
        }
        // ---- stage B: W[nb*64+el][kt*64 + kl..kl+3] ----
        #pragma unroll
        for (int it = 0; it < 4; ++it) {
            int f  = tid + it*256;
            int el = f >> 4;
            int kl = (f & 15) << 2;
            float4 w4 = *(const float4*)(W + (size_t)(nb*64 + el)*192 + kt*64 + kl);
            Bs[kl+0][el] = w4.x;
            Bs[kl+1][el] = w4.y;
            Bs[kl+2][el] = w4.z;
            Bs[kl+3][el] = w4.w;
        }
        __syncthreads();

        #pragma unroll 8
        for (int k = 0; k < 64; ++k) {
            float4 a4 = *(const float4*)&As[k][tj << 2];   // 4 j
            float4 b4 = *(const float4*)&Bs[k][te << 2];   // 4 e
            acc[0][0] += a4.x*b4.x; acc[0][1] += a4.x*b4.y; acc[0][2] += a4.x*b4.z; acc[0][3] += a4.x*b4.w;
            acc[1][0] += a4.y*b4.x; acc[1][1] += a4.y*b4.y; acc[1][2] += a4.y*b4.z; acc[1][3] += a4.y*b4.w;
            acc[2][0] += a4.z*b4.x; acc[2][1] += a4.z*b4.y; acc[2][2] += a4.z*b4.z; acc[2][3] += a4.z*b4.w;
            acc[3][0] += a4.w*b4.x; acc[3][1] += a4.w*b4.y; acc[3][2] += a4.w*b4.z; acc[3][3] += a4.w*b4.w;
        }
        __syncthreads();
    }

    // ---- epilogue: +bias, scatter to pixel layout (float4 over 4 consecutive pj) ----
    const int e0   = nb*64 + te*4;       // global e (within one slot & one channel)
    const int slot = nb / 3;             // 0=q 1=k 2=v
    const int c    = nb % 3;
    const int dl   = (te*4) & 63;        // pi*8 + pj0
    const int pi   = dl >> 3;
    const int pj0  = dl & 7;             // 0 or 4
    float4 bias4 = *(const float4*)(bqkv + e0);
    float* base = ws + (size_t)slot * PLANE
                + (((size_t)(b*3 + c))*HW + (size_t)(i*8 + pi))*HW + pj0;
    #pragma unroll
    for (int jj = 0; jj < 4; ++jj) {
        int j = (tj << 2) + jj;
        float4 o;
        o.x = acc[jj][0] + bias4.x;
        o.y = acc[jj][1] + bias4.y;
        o.z = acc[jj][2] + bias4.z;
        o.w = acc[jj][3] + bias4.w;
        *(float4*)(base + j*8) = o;
    }
}

__global__ void __launch_bounds__(256) attn_stencil_kernel(
    const float* __restrict__ ws,
    const float* __restrict__ bqkv,
    float* __restrict__ out)
{
    int g  = blockIdx.x * 256 + threadIdx.x;   // float4 id
    int px = g << 2;                           // pixel float index
    int x  = px & 511;
    int y  = (px >> 9) & 511;
    int c  = (px >> 18) % 3;
    int pi  = y & 7;
    int pj0 = x & 7;                           // 0 or 4

    // separable relative-position bias factors
    float fr[3];
    fr[0] = __expf((float)(pi - 7) * 0.25f);
    fr[1] = 1.f;
    fr[2] = __expf((float)(-pi) * 0.25f);
    float fcx[3][4];
    #pragma unroll
    for (int w = 0; w < 4; ++w) {
        int pj = pj0 + w;
        fcx[0][w] = __expf((float)(pj - 7) * 0.25f);
        fcx[1][w] = 1.f;
        fcx[2][w] = __expf((float)(-pj) * 0.25f);
    }

    int d0 = c*64 + pi*8 + pj0;
    float4 bk4 = *(const float4*)(bqkv + 192 + d0);   // zero-patch k constant
    float4 bv4 = *(const float4*)(bqkv + 384 + d0);   // zero-patch v constant

    const float* qp = ws;
    const float* kp = ws + PLANE;
    const float* vp = ws + 2*(size_t)PLANE;

    float4 q4 = *(const float4*)(qp + px);
    float ax = 0.f, ay = 0.f, az = 0.f, aw = 0.f;

    #pragma unroll
    for (int di = 0; di < 3; ++di) {
        int yy = y + (di - 1)*8;
        bool rok = (unsigned)yy < 512u;
        #pragma unroll
        for (int dj = 0; dj < 3; ++dj) {
            int xx = x + (dj - 1)*8;
            bool cok = (unsigned)xx < 512u;
            float4 k4, v4;
            if (rok && cok) {
                int pn = px + (di - 1)*4096 + (dj - 1)*8;
                k4 = *(const float4*)(kp + pn);
                v4 = *(const float4*)(vp + pn);
            } else {
                k4 = bk4; v4 = bv4;
            }
            float f = fr[di];
            ax += f * fcx[dj][0] * k4.x * v4.x;
            ay += f * fcx[dj][1] * k4.y * v4.y;
            az += f * fcx[dj][2] * k4.z * v4.z;
            aw += f * fcx[dj][3] * k4.w * v4.w;
        }
    }
    float4 o;
    o.x = q4.x * ax;
    o.y = q4.y * ay;
    o.z = q4.z * az;
    o.w = q4.w * aw;
    *(float4*)(out + px) = o;
}

extern "C" void kernel_launch(void* const* d_in, const int* in_sizes, int n_in,
                              void* d_out, int out_size, void* d_ws, size_t ws_size,
                              hipStream_t stream)
{
    const float* x  = (const float*)d_in[0];   // [8][3][512][512]
    const float* W  = (const float*)d_in[1];   // [576][192]
    const float* bq = (const float*)d_in[2];   // [576]
    float* ws   = (float*)d_ws;                // needs 3*PLANE*4 = 75.5 MB
    float* outp = (float*)d_out;               // [8][3][512][512]

    dim3 g1(512, 9);                           // (b*64+i) x e-chunk
    qkv_gemm_kernel<<<g1, 256, 0, stream>>>(x, W, bq, ws);

    attn_stencil_kernel<<<PLANE/1024, 256, 0, stream>>>(ws, bq, outp);  // 6144 blocks
}

// Round 4
// 123.303 us; speedup vs baseline: 1.5801x; 1.5801x over previous
//
#include <hip/hip_runtime.h>

// AttentionConv on MI355X (gfx950).
// prep : split W into bf16 hi/lo planes, pre-swizzled for LDS unit layout.
// phase1: per-patch QKV GEMM (M=32768,K=192,N=576) via bf16x3-split MFMA.
//         Writes q-plane and w = k*v plane (pixel layout) to d_ws.
// phase2: out = q * sum_{di,dj} fr(di,pi)*fc(dj,pj) * w_shifted, LDS-tiled
//         (64x64 tile + 8-halo; OOB neighbors use b_qkv constant products).

#define HW 512
#define PLANE 6291456   // 8*3*512*512 floats per plane

typedef __attribute__((ext_vector_type(8))) short bf16x8;
typedef __attribute__((ext_vector_type(4))) float f32x4;

static __device__ __forceinline__ unsigned short bf16_rne(float f) {
    unsigned u = __builtin_bit_cast(unsigned, f);
    u += 0x7FFFu + ((u >> 16) & 1u);
    return (unsigned short)(u >> 16);
}
static __device__ __forceinline__ float bf16f(unsigned short h) {
    unsigned u = ((unsigned)h) << 16;
    return __builtin_bit_cast(float, u);
}

// ---------------- prep: W -> bf16 hi/lo, unit-swizzled ----------------
// Ws layout (ushort): [ckt=c*3+kt][half: 0=hi 1=lo][er=slot*64+dl][64 k]
// within a row, 16B units permuted: unit ^= (er&7)  (matches LDS read swizzle)
__global__ void __launch_bounds__(256) wprep_kernel(const float* __restrict__ W,
                                                    unsigned short* __restrict__ Ws)
{
    int gid = blockIdx.x * 256 + threadIdx.x;   // 27648 = 108*256 exact
    int k4  = gid & 15;
    int t   = gid >> 4;
    int er  = t % 192;
    int ckt = t / 192;                          // c*3 + kt
    int c   = ckt / 3, kt = ckt % 3;
    int k0  = k4 << 2;
    int slot = er >> 6, dl = er & 63;
    const float* src = W + (size_t)(slot*192 + c*64 + dl)*192 + kt*64 + k0;
    float4 v = *(const float4*)src;
    unsigned short h0 = bf16_rne(v.x), h1 = bf16_rne(v.y), h2 = bf16_rne(v.z), h3 = bf16_rne(v.w);
    unsigned short l0 = bf16_rne(v.x - bf16f(h0)), l1 = bf16_rne(v.y - bf16f(h1)),
                   l2 = bf16_rne(v.z - bf16f(h2)), l3 = bf16_rne(v.w - bf16f(h3));
    int unit = (k0 >> 3) ^ (er & 7);
    size_t off = (size_t)ckt*24576 + (size_t)er*64 + unit*8 + (k0 & 7);
    *(uint2*)(Ws + off)         = make_uint2((unsigned)h0 | ((unsigned)h1 << 16),
                                             (unsigned)h2 | ((unsigned)h3 << 16));
    *(uint2*)(Ws + off + 12288) = make_uint2((unsigned)l0 | ((unsigned)l1 << 16),
                                             (unsigned)l2 | ((unsigned)l3 << 16));
}

// ---------------- phase 1: bf16x3 MFMA GEMM ----------------
// grid (512, 3): blockIdx.x = b*64+i (tile-row), blockIdx.y = c.
// Block tile: 64 patches (j) x 192 e (3 slots x 64 dl for channel c).
// 4 waves, each 64(M) x 48(N) via 4x3 fragments of mfma_f32_16x16x32_bf16.
__global__ void __launch_bounds__(256) qkv_mfma_kernel(
    const float* __restrict__ x,
    const unsigned short* __restrict__ Ws,
    const float* __restrict__ bqkv,
    float* __restrict__ ws)
{
    __shared__ char smem[65536];
    unsigned short* Ah = (unsigned short*)smem;   // [64][64] bf16, swizzled rows (8KB)
    unsigned short* Al = Ah + 4096;               // 8KB
    // B hi: smem+16384 (24KB), B lo: smem+40960 (24KB) — copied pre-swizzled

    const int tid = threadIdx.x;
    const int mb  = blockIdx.x;
    const int c   = blockIdx.y;
    const int b   = mb >> 6, i = mb & 63;
    const int wv  = tid >> 6;          // wave 0..3
    const int l   = tid & 63;
    const int lr  = l & 15;            // fragment row/col index
    const int lk  = l >> 4;            // k-group

    f32x4 acc[4][3];
    #pragma unroll
    for (int m = 0; m < 4; ++m)
        #pragma unroll
        for (int n = 0; n < 3; ++n)
            #pragma unroll
            for (int r = 0; r < 4; ++r) acc[m][n][r] = 0.f;

    for (int kt = 0; kt < 3; ++kt) {
        // ---- stage A: convert x slab (8 rows x 512) to hi/lo bf16, swizzled ----
        const float4* xs = (const float4*)(x + ((size_t)(b*3 + kt)*HW + (size_t)i*8) * HW);
        #pragma unroll
        for (int it = 0; it < 4; ++it) {
            int f  = tid + it*256;             // 0..1023 float4
            float4 a = xs[f];
            int pi = f >> 7;
            int m_ = f & 127;
            int j  = m_ >> 1;
            int k  = pi*8 + ((m_ & 1) << 2);
            unsigned short h0 = bf16_rne(a.x), h1 = bf16_rne(a.y), h2 = bf16_rne(a.z), h3 = bf16_rne(a.w);
            unsigned short q0 = bf16_rne(a.x - bf16f(h0)), q1 = bf16_rne(a.y - bf16f(h1)),
                           q2 = bf16_rne(a.z - bf16f(h2)), q3 = bf16_rne(a.w - bf16f(h3));
            int byte = (j*128 + k*2) ^ ((j & 7) << 4);
            *(uint2*)((char*)Ah + byte) = make_uint2((unsigned)h0 | ((unsigned)h1 << 16),
                                                     (unsigned)h2 | ((unsigned)h3 << 16));
            *(uint2*)((char*)Al + byte) = make_uint2((unsigned)q0 | ((unsigned)q1 << 16),
                                                     (unsigned)q2 | ((unsigned)q3 << 16));
        }
        // ---- stage B: straight copy of pre-split, pre-swizzled slab (48KB) ----
        {
            const uint4* bsrc = (const uint4*)(Ws + (size_t)(c*3 + kt)*24576);
            uint4* bdst = (uint4*)(smem + 16384);
            #pragma unroll
            for (int it = 0; it < 12; ++it) bdst[tid + it*256] = bsrc[tid + it*256];
        }
        __syncthreads();

        // ---- MFMA: 2 k-steps of 32; 3 split-products each ----
        #pragma unroll
        for (int ks = 0; ks < 2; ++ks) {
            const int kb = (ks*32 + lk*8) * 2;    // byte offset of this lane's 8 k's
            bf16x8 ahf[4], alf[4], bhf[3], blf[3];
            #pragma unroll
            for (int m = 0; m < 4; ++m) {
                int row = m*16 + lr;
                int byte = (row*128 + kb) ^ ((row & 7) << 4);
                ahf[m] = *(const bf16x8*)((const char*)Ah + byte);
                alf[m] = *(const bf16x8*)((const char*)Al + byte);
            }
            #pragma unroll
            for (int n = 0; n < 3; ++n) {
                int er = wv*48 + n*16 + lr;
                int byte = (er*128 + kb) ^ ((er & 7) << 4);
                bhf[n] = *(const bf16x8*)(smem + 16384 + byte);
                blf[n] = *(const bf16x8*)(smem + 40960 + byte);
            }
            #pragma unroll
            for (int m = 0; m < 4; ++m)
                #pragma unroll
                for (int n = 0; n < 3; ++n) {
                    acc[m][n] = __builtin_amdgcn_mfma_f32_16x16x32_bf16(alf[m], bhf[n], acc[m][n], 0, 0, 0);
                    acc[m][n] = __builtin_amdgcn_mfma_f32_16x16x32_bf16(ahf[m], blf[n], acc[m][n], 0, 0, 0);
                    acc[m][n] = __builtin_amdgcn_mfma_f32_16x16x32_bf16(ahf[m], bhf[n], acc[m][n], 0, 0, 0);
                }
        }
        __syncthreads();
    }

    // ---- epilogue: frags -> f32 LDS tiles (+bias), then q and w=k*v to global ----
    float* qt  = (float*)smem;         // [64][68] f32
    float* ktl = qt + 4352;
    float* vtl = ktl + 4352;
    #pragma unroll
    for (int n = 0; n < 3; ++n) {
        int er = wv*48 + n*16 + lr;
        int slot = er >> 6, dl = er & 63;
        float bias = bqkv[slot*192 + c*64 + dl];
        float* tile = (slot == 0) ? qt : (slot == 1) ? ktl : vtl;
        #pragma unroll
        for (int m = 0; m < 4; ++m)
            #pragma unroll
            for (int ri = 0; ri < 4; ++ri) {
                int j = m*16 + lk*4 + ri;          // D row = (l>>4)*4 + reg  [m89]
                tile[j*68 + dl] = acc[m][n][ri] + bias;
            }
    }
    __syncthreads();

    float* qplane = ws;
    float* wplane = ws + PLANE;
    size_t pixbase = ((size_t)(b*3 + c)*HW + (size_t)i*8) * HW;
    #pragma unroll
    for (int it = 0; it < 4; ++it) {
        int f  = tid + it*256;                     // pixel-order float4
        int pi = f >> 7;
        int m_ = f & 127;
        int j  = m_ >> 1;
        int dl = pi*8 + ((m_ & 1) << 2);
        float4 q4 = *(float4*)&qt[j*68 + dl];
        float4 k4 = *(float4*)&ktl[j*68 + dl];
        float4 v4 = *(float4*)&vtl[j*68 + dl];
        size_t off = pixbase + (size_t)pi*HW + m_*4;
        *(float4*)(qplane + off) = q4;
        float4 w4;
        w4.x = k4.x*v4.x; w4.y = k4.y*v4.y; w4.z = k4.z*v4.z; w4.w = k4.w*v4.w;
        *(float4*)(wplane + off) = w4;
    }
}

// ---------------- phase 2: LDS-tiled 9-tap stencil ----------------
__global__ void __launch_bounds__(256) attn_kernel(
    const float* __restrict__ ws,
    const float* __restrict__ bqkv,
    float* __restrict__ out)
{
    __shared__ float wt[80][84];                  // 64x64 tile + 8 halo, padded
    const int tid = threadIdx.x;
    int bid = blockIdx.x;
    int txt = (bid & 7) << 6;
    int tyt = ((bid >> 3) & 7) << 6;
    int pl  = bid >> 6;                           // b*3 + c
    int c   = pl % 3;
    const float* qplane = ws + (size_t)pl * (HW*HW);
    const float* wplane = ws + PLANE + (size_t)pl * (HW*HW);

    for (int it = 0; it < 7; ++it) {
        int f = tid + it*256;
        if (f < 1600) {                           // 80 rows x 20 float4
            int r  = f / 20;
            int c4 = f - r*20;
            int gy = tyt - 8 + r;
            int gx = txt - 8 + (c4 << 2);
            float4 v;
            if ((unsigned)gy < 512u && (unsigned)gx < 512u) {
                v = *(const float4*)(wplane + (size_t)gy*HW + gx);
            } else {                              // OOB patch: w = bk*bv constant
                int d0 = c*64 + (gy & 7)*8 + (gx & 7);
                float4 bk = *(const float4*)(bqkv + 192 + d0);
                float4 bv = *(const float4*)(bqkv + 384 + d0);
                v.x = bk.x*bv.x; v.y = bk.y*bv.y; v.z = bk.z*bv.z; v.w = bk.w*bv.w;
            }
            *(float4*)&wt[r][c4 << 2] = v;
        }
    }
    __syncthreads();

    #pragma unroll
    for (int it = 0; it < 4; ++it) {
        int f  = tid + it*256;
        int ly = f >> 4;
        int lx = (f & 15) << 2;
        int pi = ly & 7, pj0 = lx & 7;
        float fr0 = __expf((float)(pi - 7) * 0.25f);
        float fr2 = __expf((float)(-pi) * 0.25f);
        float fa[4], fb[4];
        #pragma unroll
        for (int u = 0; u < 4; ++u) {
            int pj = pj0 + u;
            fa[u] = __expf((float)(pj - 7) * 0.25f);
            fb[u] = __expf((float)(-pj) * 0.25f);
        }
        float sx = 0.f, sy = 0.f, sz = 0.f, sw = 0.f;
        #pragma unroll
        for (int di = 0; di < 3; ++di) {
            const float* row = &wt[ly + 8*di][lx];
            float4 w0 = *(const float4*)(row);
            float4 w1 = *(const float4*)(row + 8);
            float4 w2 = *(const float4*)(row + 16);
            float fr = (di == 0) ? fr0 : (di == 1) ? 1.f : fr2;
            sx += fr * (fa[0]*w0.x + w1.x + fb[0]*w2.x);
            sy += fr * (fa[1]*w0.y + w1.y + fb[1]*w2.y);
            sz += fr * (fa[2]*w0.z + w1.z + fb[2]*w2.z);
            sw += fr * (fa[3]*w0.w + w1.w + fb[3]*w2.w);
        }
        size_t off = (size_t)pl*(HW*HW) + (size_t)(tyt + ly)*HW + txt + lx;
        float4 q4 = *(const float4*)(qplane + (size_t)(tyt + ly)*HW + txt + lx);
        float4 o;
        o.x = q4.x*sx; o.y = q4.y*sy; o.z = q4.z*sz; o.w = q4.w*sw;
        *(float4*)(out + off) = o;
    }
}

extern "C" void kernel_launch(void* const* d_in, const int* in_sizes, int n_in,
                              void* d_out, int out_size, void* d_ws, size_t ws_size,
                              hipStream_t stream)
{
    const float* x  = (const float*)d_in[0];   // [8][3][512][512]
    const float* W  = (const float*)d_in[1];   // [576][192]
    const float* bq = (const float*)d_in[2];   // [576]
    float* wsf = (float*)d_ws;                 // q-plane | w-plane | W-split (50.8 MB)
    unsigned short* Wsplit = (unsigned short*)(wsf + 2*(size_t)PLANE);

    wprep_kernel<<<108, 256, 0, stream>>>(W, Wsplit);
    qkv_mfma_kernel<<<dim3(512, 3), 256, 0, stream>>>(x, Wsplit, bq, wsf);
    attn_kernel<<<1536, 256, 0, stream>>>(wsf, bq, (float*)d_out);
}